// Round 7
// baseline (314.913 us; speedup 1.0000x reference)
//
#include <hip/hip_runtime.h>
#include <hip/hip_bf16.h>
#include <math.h>

#define NCLS 20
#define KDIM 128
#define ALPHA 0.7f
#define BETA 1.5f

// ws layout (floats): [0, NCLS*KDIM) class sums; [NCLS*KDIM, +NCLS) counts;
// [WS_INTRA, +NCLS) intra partials; [WS_AB, +8) diagnostic sinks.
#define WS_SUMS 0
#define WS_CNT (NCLS * KDIM)
#define WS_INTRA (NCLS * KDIM + NCLS)
#define WS_TOTAL (NCLS * KDIM + 2 * NCLS)
#define WS_AB WS_TOTAL
#define WS_FULL (WS_TOTAL + 8)

#define GRID 2048

__global__ void k_init(float* ws) {
    int i = blockIdx.x * blockDim.x + threadIdx.x;
    if (i < WS_FULL) ws[i] = 0.0f;
}

// ---------- REAL pass 1: k_intra-shaped loads + exclusive-ownership scatter ----------
// 256 thr = 4 waves. Wave covers 2 consecutive points per slot (lanes 0-31 =
// point A's 32 float4s, lanes 32-63 = point B) -> one 1KB coalesced dwordx4,
// identical to k_intra's load stream. Per-wave private LDS copy; halves write
// different class rows unless cA==cB (then shfl_xor(32) combine, half 0 writes).
__global__ void __launch_bounds__(256) k_sums(const float4* __restrict__ emb4,
                                              const int* __restrict__ t,
                                              float* __restrict__ ws, int N) {
    __shared__ float lsum[4][NCLS * KDIM];   // 40KB: one copy per wave
    __shared__ float lcnt[NCLS];
    const int tid = threadIdx.x;
    const int w = tid >> 6;
    const int s = tid & 31;
    const int pp = tid >> 5;          // 0..7: which point slot in the block
    const int half = pp & 1;          // half of the wave

    for (int i = tid; i < 4 * NCLS * KDIM; i += 256) (&lsum[0][0])[i] = 0.0f;
    if (tid < NCLS) lcnt[tid] = 0.0f;
    __syncthreads();

    float* L = lsum[w];
    const int stride = GRID * 8;

    for (int base = blockIdx.x * 8; base < N; base += 2 * stride) {
#define POINT(PBASE)                                                          \
        {                                                                     \
            const int p = (PBASE) + pp;                                       \
            const bool ok = p < N;                                            \
            const int c = ok ? t[p] : 0;                                      \
            float4 v = ok ? emb4[(size_t)p * 32 + s]                          \
                          : make_float4(0.f, 0.f, 0.f, 0.f);                  \
            const int cA = __shfl(c, 0, 64);                                  \
            const int cB = __shfl(c, 32, 64);                                 \
            if (cA == cB) {                                                   \
                float4 vv;                                                    \
                vv.x = v.x + __shfl_xor(v.x, 32, 64);                         \
                vv.y = v.y + __shfl_xor(v.y, 32, 64);                         \
                vv.z = v.z + __shfl_xor(v.z, 32, 64);                         \
                vv.w = v.w + __shfl_xor(v.w, 32, 64);                         \
                if (half == 0 && ok) {                                        \
                    float4* a = (float4*)&L[cA * KDIM + 4 * s];               \
                    float4 o = *a;                                            \
                    o.x += vv.x; o.y += vv.y; o.z += vv.z; o.w += vv.w;       \
                    *a = o;                                                   \
                }                                                             \
            } else if (ok) {                                                  \
                float4* a = (float4*)&L[c * KDIM + 4 * s];                    \
                float4 o = *a;                                                \
                o.x += v.x; o.y += v.y; o.z += v.z; o.w += v.w;               \
                *a = o;                                                       \
            }                                                                 \
            if (s == 0 && ok) unsafeAtomicAdd(&lcnt[c], 1.0f);                \
        }
        POINT(base)
        POINT(base + stride)
#undef POINT
    }
    __syncthreads();

    for (int i = tid; i < NCLS * KDIM; i += 256)
        unsafeAtomicAdd(&ws[WS_SUMS + i],
                        lsum[0][i] + lsum[1][i] + lsum[2][i] + lsum[3][i]);
    if (tid < NCLS) unsafeAtomicAdd(&ws[WS_CNT + tid], lcnt[tid]);
}

// ---------- DIAG A: R6's chunked float4 loads, iso-LDS, NO per-point LDS ops ----------
#define SUMS_BLK 128
__global__ void __launch_bounds__(SUMS_BLK) k_ab_pure4c(const float4* __restrict__ emb4,
                                                        float* __restrict__ ws, int N) {
    __shared__ float lsum[2][NCLS * KDIM];  // footprint only (occupancy iso-R6)
    const int tid = threadIdx.x;
    const int w = tid >> 6, k = tid & 63;
    const int chunk = blockIdx.x * SUMS_BLK;
    float ax = 0.f, ay = 0.f, az = 0.f, aw = 0.f;
    if (chunk + SUMS_BLK <= N) {
        for (int qb = 32 * w; qb < 32 * w + 32; qb += 8) {
            float4 v0, v1, v2, v3, v4, v5, v6, v7;
#define LD(j) v##j = emb4[(size_t)(chunk + 2 * (qb + j)) * 32 + k];
            LD(0) LD(1) LD(2) LD(3) LD(4) LD(5) LD(6) LD(7)
#undef LD
#define AC(j) { ax += v##j.x; ay += v##j.y; az += v##j.z; aw += v##j.w; }
            AC(0) AC(1) AC(2) AC(3) AC(4) AC(5) AC(6) AC(7)
#undef AC
        }
    }
    lsum[w][tid] = ax + ay + az + aw;
    __syncthreads();
    float m = lsum[w][tid] + lsum[w ^ 1][tid ^ 64];  // touch both copies
    for (int off = 32; off >= 1; off >>= 1) m += __shfl_down(m, off, 64);
    if (k == 0) unsafeAtomicAdd(&ws[WS_AB + 0], m);
}

// ---------- DIAG B: k_intra's exact load shape, pure (first direct measure) ----------
__global__ void __launch_bounds__(256) k_ab_shape(const float4* __restrict__ emb4,
                                                  const int* __restrict__ t,
                                                  float* __restrict__ ws, int N) {
    __shared__ float lmean[NCLS * KDIM];  // footprint iso-k_intra
    const int tid = threadIdx.x;
    for (int i = tid; i < NCLS * KDIM; i += 256) lmean[i] = 0.0f;
    __syncthreads();
    const int s = tid & 31;
    const int pp = tid >> 5;
    const int stride = GRID * 8;
    float acc = 0.f;
    for (int p = blockIdx.x * 8 + pp; p < N; p += 2 * stride) {
        const int p1 = p + stride;
        {
            const int c = t[p];
            const float4 v = emb4[(size_t)p * 32 + s];
            acc += v.x + v.y + v.z + v.w + (float)c * 1e-20f;
        }
        if (p1 < N) {
            const int c = t[p1];
            const float4 v = emb4[(size_t)p1 * 32 + s];
            acc += v.x + v.y + v.z + v.w + (float)c * 1e-20f;
        }
    }
    acc += lmean[tid & 255];  // keep LDS live
    for (int off = 32; off >= 1; off >>= 1) acc += __shfl_down(acc, off, 64);
    if ((tid & 63) == 0) unsafeAtomicAdd(&ws[WS_AB + 1], acc);
}

// ---------- pass 2 (unchanged anchor) ----------
__global__ void __launch_bounds__(256) k_intra(const float4* __restrict__ emb4,
                                               const int* __restrict__ t,
                                               const float* __restrict__ pts,
                                               float* __restrict__ ws, int N) {
    __shared__ float lmean[NCLS * KDIM];
    __shared__ float lintra[NCLS];
    const int tid = threadIdx.x;
    for (int i = tid; i < NCLS * KDIM; i += 256) {
        float cnt = ws[WS_CNT + i / KDIM];
        lmean[i] = ws[WS_SUMS + i] / fmaxf(cnt, 1.0f);
    }
    if (tid < NCLS) lintra[tid] = 0.0f;
    __syncthreads();

    const int s = tid & 31;
    const int pp = tid >> 5;
    const int stride = GRID * 8;
    for (int p = blockIdx.x * 8 + pp; p < N; p += 2 * stride) {
        const int p1 = p + stride;
        {
            const int c = t[p];
            const float4 v = emb4[(size_t)p * 32 + s];
            const float4 m = *(const float4*)&lmean[c * KDIM + 4 * s];
            float dx = v.x - m.x, dy = v.y - m.y, dz = v.z - m.z, dw = v.w - m.w;
            float d2 = dx * dx + dy * dy + dz * dz + dw * dw;
            for (int off = 16; off >= 1; off >>= 1) d2 += __shfl_down(d2, off, 32);
            if (s == 0) {
                float d = sqrtf(d2);
                float px = pts[(size_t)p * 3 + 0];
                float py = pts[(size_t)p * 3 + 1];
                float pz = pts[(size_t)p * 3 + 2];
                float r = sqrtf(px * px + py * py + pz * pz);
                float g = 1.0f / (1.0f + expf(-r));
                float h = fmaxf(d - ALPHA, 0.0f);
                unsafeAtomicAdd(&lintra[c], g * h * h);
            }
        }
        if (p1 < N) {
            const int c = t[p1];
            const float4 v = emb4[(size_t)p1 * 32 + s];
            const float4 m = *(const float4*)&lmean[c * KDIM + 4 * s];
            float dx = v.x - m.x, dy = v.y - m.y, dz = v.z - m.z, dw = v.w - m.w;
            float d2 = dx * dx + dy * dy + dz * dz + dw * dw;
            for (int off = 16; off >= 1; off >>= 1) d2 += __shfl_down(d2, off, 32);
            if (s == 0) {
                float d = sqrtf(d2);
                float px = pts[(size_t)p1 * 3 + 0];
                float py = pts[(size_t)p1 * 3 + 1];
                float pz = pts[(size_t)p1 * 3 + 2];
                float r = sqrtf(px * px + py * py + pz * pz);
                float g = 1.0f / (1.0f + expf(-r));
                float h = fmaxf(d - ALPHA, 0.0f);
                unsafeAtomicAdd(&lintra[c], g * h * h);
            }
        }
    }
    __syncthreads();
    if (tid < NCLS) unsafeAtomicAdd(&ws[WS_INTRA + tid], lintra[tid]);
}

// ---------- final (unchanged) ----------
__global__ void __launch_bounds__(256) k_final(const float* __restrict__ ws,
                                               float* __restrict__ out) {
    __shared__ float lmean[NCLS * KDIM];
    __shared__ float red[256];
    const int tid = threadIdx.x;
    for (int i = tid; i < NCLS * KDIM; i += 256) {
        float cnt = ws[WS_CNT + i / KDIM];
        lmean[i] = ws[WS_SUMS + i] / fmaxf(cnt, 1.0f);
    }
    __syncthreads();

    float acc = 0.0f;
    for (int idx = tid; idx < 361; idx += 256) {
        int i = idx / 19 + 1;
        int j = idx % 19 + 1;
        if (i != j) {
            float sq = 0.0f;
            const float* mi = lmean + i * KDIM;
            const float* mj = lmean + j * KDIM;
            for (int k = 0; k < KDIM; k++) {
                float df = mi[k] - mj[k];
                sq += df * df;
            }
            float dist = sqrtf(sq);
            float h = fmaxf(BETA - dist, 0.0f);
            acc += h * h;
        }
    }
    red[tid] = acc;
    __syncthreads();
    for (int st = 128; st >= 1; st >>= 1) {
        if (tid < st) red[tid] += red[tid + st];
        __syncthreads();
    }
    if (tid == 0) {
        float intra = 0.0f;
        for (int c = 1; c < NCLS; c++) {
            intra += ws[WS_INTRA + c] / fmaxf(ws[WS_CNT + c], 1.0f);
        }
        out[0] = intra / (float)NCLS + red[0] / (float)(NCLS * (NCLS - 1));
    }
}

extern "C" void kernel_launch(void* const* d_in, const int* in_sizes, int n_in,
                              void* d_out, int out_size, void* d_ws, size_t ws_size,
                              hipStream_t stream) {
    const float* pts = (const float*)d_in[0];
    const int* t = (const int*)d_in[1];
    const float4* emb4 = (const float4*)d_in[2];
    float* out = (float*)d_out;
    float* ws = (float*)d_ws;
    const int N = in_sizes[1];

    k_init<<<(WS_FULL + 255) / 256, 256, 0, stream>>>(ws);
    k_sums<<<GRID, 256, 0, stream>>>(emb4, t, ws, N);
    k_intra<<<GRID, 256, 0, stream>>>(emb4, t, pts, ws, N);
    k_final<<<1, 256, 0, stream>>>(ws, out);

    // diagnostics (sink-writing; after the real pipeline)
    if (ws_size >= WS_FULL * sizeof(float)) {
        k_ab_pure4c<<<GRID, SUMS_BLK, 0, stream>>>(emb4, ws, N);
        k_ab_shape<<<GRID, 256, 0, stream>>>(emb4, t, ws, N);
    }
}

// Round 8
// 106.269 us; speedup vs baseline: 2.9634x; 2.9634x over previous
//
#include <hip/hip_runtime.h>
#include <hip/hip_bf16.h>
#include <math.h>

#define NCLS 20
#define KDIM 128
#define ALPHA 0.7f
#define BETA 1.5f

// ws float layout:
// [0,2560) class sums | [2560,+20) counts(float) | [2580,+20) intra partials
// [2600,+20) hist(int) | [2620,+20) cursors(int) | [4096, +524288) int2 pairs
#define WS_SUMS 0
#define WS_CNT (NCLS * KDIM)
#define WS_INTRA (NCLS * KDIM + NCLS)
#define WS_HIST (NCLS * KDIM + 2 * NCLS)
#define WS_CUR (NCLS * KDIM + 3 * NCLS)
#define WS_ZERO 4096
#define WS_PAIRS 4096
#define WS_NEEDED ((WS_PAIRS + 2 * 262144) * 4)

#define GRID 2048

__global__ void k_init(float* ws) {
    int i = blockIdx.x * blockDim.x + threadIdx.x;
    if (i < WS_ZERO) ws[i] = 0.0f;
}

// ---- S1: class histogram (reads t only, 1MB, int4) ----
__global__ void __launch_bounds__(256) k_hist(const int4* __restrict__ t4,
                                              float* __restrict__ ws, int N4) {
    __shared__ int h[NCLS];
    const int tid = threadIdx.x;
    if (tid < NCLS) h[tid] = 0;
    __syncthreads();
    const int gid = blockIdx.x * 256 + tid;
    if (gid < N4) {
        const int4 c = t4[gid];
        atomicAdd(&h[c.x], 1);
        atomicAdd(&h[c.y], 1);
        atomicAdd(&h[c.z], 1);
        atomicAdd(&h[c.w], 1);
    }
    __syncthreads();
    if (tid < NCLS) atomicAdd((int*)&ws[WS_HIST] + tid, h[tid]);
}

// ---- S2: exclusive scan of 20 counts -> cursors; counts -> float ----
__global__ void k_scan(float* __restrict__ ws) {
    if (threadIdx.x == 0) {
        const int* h = (const int*)&ws[WS_HIST];
        int* cur = (int*)&ws[WS_CUR];
        int run = 0;
        for (int c = 0; c < NCLS; c++) {
            cur[c] = run;
            ws[WS_CNT + c] = (float)h[c];
            run += h[c];
        }
    }
}

// ---- S3: scatter (class, idx) pairs into class-sorted order ----
__global__ void __launch_bounds__(256) k_scatter(const int4* __restrict__ t4,
                                                 float* __restrict__ ws, int N4) {
    __shared__ int h[NCLS], lbase[NCLS], lcur[NCLS];
    const int tid = threadIdx.x;
    if (tid < NCLS) { h[tid] = 0; lcur[tid] = 0; }
    __syncthreads();
    const int gid = blockIdx.x * 256 + tid;
    int4 c4 = make_int4(0, 0, 0, 0);
    if (gid < N4) {
        c4 = t4[gid];
        atomicAdd(&h[c4.x], 1);
        atomicAdd(&h[c4.y], 1);
        atomicAdd(&h[c4.z], 1);
        atomicAdd(&h[c4.w], 1);
    }
    __syncthreads();
    if (tid < NCLS) lbase[tid] = atomicAdd((int*)&ws[WS_CUR] + tid, h[tid]);
    __syncthreads();
    if (gid < N4) {
        int2* pairs = (int2*)&ws[WS_PAIRS];
        const int p0 = gid * 4;
        int cc[4] = {c4.x, c4.y, c4.z, c4.w};
        for (int j = 0; j < 4; j++) {
            const int c = cc[j];
            const int dst = lbase[c] + atomicAdd(&lcur[c], 1);
            pairs[dst] = make_int2(c, p0 + j);
        }
    }
}

// ---- pass 1: sorted segment-sum. Half-wave owns 32 consecutive sorted
// positions; per point: one uniform 8B pair load + one 16B emb gather +
// float4 register add; LDS flush only on class change (rare). ----
#define SUMS_GRID 1024
__global__ void __launch_bounds__(256) k_sums(const float4* __restrict__ emb4,
                                              const float* __restrict__ ws_ro,
                                              float* __restrict__ ws, int N) {
    __shared__ float lsum[NCLS * KDIM];
    const int tid = threadIdx.x;
    for (int i = tid; i < NCLS * KDIM; i += 256) lsum[i] = 0.0f;
    __syncthreads();

    const int s = tid & 31;
    const int hw = blockIdx.x * 8 + (tid >> 5);   // 0..8191
    const int2* pairs = (const int2*)&ws_ro[WS_PAIRS];
    const int base = hw * 32;

#define FLUSHA(C, A)                                                \
    {                                                               \
        float* a = &lsum[(C) * KDIM + 4 * s];                       \
        unsafeAtomicAdd(a + 0, (A).x);                              \
        unsafeAtomicAdd(a + 1, (A).y);                              \
        unsafeAtomicAdd(a + 2, (A).z);                              \
        unsafeAtomicAdd(a + 3, (A).w);                              \
    }

    if (base < N) {
        int2 pr = pairs[base];
        int ccur = __builtin_amdgcn_readfirstlane(pr.x);
        float4 acc = emb4[(size_t)pr.y * 32 + s];
        for (int j0 = 4; j0 <= 32; j0 += 4) {
            // prefetch batch of 4 (independent loads)
            int2 q0, q1, q2, q3;
            float4 v0, v1, v2, v3;
            const bool more = j0 < 32;
            if (more) {
                q0 = pairs[base + j0 + 0];
                q1 = pairs[base + j0 + 1];
                q2 = pairs[base + j0 + 2];
                q3 = pairs[base + j0 + 3];
                v0 = emb4[(size_t)q0.y * 32 + s];
                v1 = emb4[(size_t)q1.y * 32 + s];
                v2 = emb4[(size_t)q2.y * 32 + s];
                v3 = emb4[(size_t)q3.y * 32 + s];
            }
            // merge previous batch positions j0-3..j0-1 (first batch: 1..3)
            const int lo = j0 - 4 ? j0 - 4 : 1;
            for (int j = lo; j < j0; j++) {
                int2 q = pairs[base + j];
                float4 v = emb4[(size_t)q.y * 32 + s];
                const int c = __builtin_amdgcn_readfirstlane(q.x);
                if (c != ccur) {
                    FLUSHA(ccur, acc);
                    ccur = c;
                    acc = v;
                } else {
                    acc.x += v.x; acc.y += v.y; acc.z += v.z; acc.w += v.w;
                }
            }
            (void)more; (void)q0; (void)q1; (void)q2; (void)q3;
            (void)v0; (void)v1; (void)v2; (void)v3;
        }
        FLUSHA(ccur, acc);
    }
#undef FLUSHA
    __syncthreads();

    for (int i = tid; i < NCLS * KDIM; i += 256)
        if (lsum[i] != 0.0f) unsafeAtomicAdd(&ws[WS_SUMS + i], lsum[i]);
}

// ---- fallback pass 1 (R6-proven, used only if ws too small) ----
#define FB_BLK 128
#define FB_GRID 2048
__global__ void __launch_bounds__(FB_BLK) k_sums_fb(const float4* __restrict__ emb4,
                                                    const int* __restrict__ t,
                                                    float* __restrict__ ws, int N) {
    __shared__ float lsum[2][NCLS * KDIM];
    __shared__ float lcnt[NCLS];
    __shared__ int lds_t[FB_BLK];
    const int tid = threadIdx.x;
    const int w = tid >> 6, k = tid & 63;
    const int half = k >> 5;
    const int k31 = k & 31;
    for (int i = tid; i < 2 * NCLS * KDIM; i += FB_BLK) (&lsum[0][0])[i] = 0.0f;
    if (tid < NCLS) lcnt[tid] = 0.0f;
    __syncthreads();
    const int chunk = blockIdx.x * FB_BLK;
    const int npts = min(FB_BLK, N - chunk);
    if (tid < npts) {
        const int c = t[chunk + tid];
        lds_t[tid] = c;
        unsafeAtomicAdd(&lcnt[c], 1.0f);
    }
    __syncthreads();
    float* L = lsum[w];
    for (int q = 32 * w; q < 32 * w + 32; q++) {
        const int pl = 2 * q + half;
        if (pl < npts) {
            const int c = lds_t[pl];
            const float4 v = emb4[(size_t)(chunk + pl) * 32 + k31];
            const int cA = __shfl(c, 0, 64);
            const int cB = __shfl(c, 32, 64);
            if (cA == cB) {
                float4 vv;
                vv.x = v.x + __shfl_xor(v.x, 32, 64);
                vv.y = v.y + __shfl_xor(v.y, 32, 64);
                vv.z = v.z + __shfl_xor(v.z, 32, 64);
                vv.w = v.w + __shfl_xor(v.w, 32, 64);
                if (half == 0) {
                    float4* a = (float4*)&L[cA * KDIM + 4 * k31];
                    float4 o = *a;
                    o.x += vv.x; o.y += vv.y; o.z += vv.z; o.w += vv.w;
                    *a = o;
                }
            } else {
                float4* a = (float4*)&L[c * KDIM + 4 * k31];
                float4 o = *a;
                o.x += v.x; o.y += v.y; o.z += v.z; o.w += v.w;
                *a = o;
            }
        }
    }
    __syncthreads();
    for (int i = tid; i < NCLS * KDIM; i += FB_BLK)
        unsafeAtomicAdd(&ws[WS_SUMS + i], lsum[0][i] + lsum[1][i]);
    if (tid < NCLS) unsafeAtomicAdd(&ws[WS_CNT + tid], lcnt[tid]);
}

// ---- pass 2 (proven ~5us warm; unchanged) ----
__global__ void __launch_bounds__(256) k_intra(const float4* __restrict__ emb4,
                                               const int* __restrict__ t,
                                               const float* __restrict__ pts,
                                               float* __restrict__ ws, int N) {
    __shared__ float lmean[NCLS * KDIM];
    __shared__ float lintra[NCLS];
    const int tid = threadIdx.x;
    for (int i = tid; i < NCLS * KDIM; i += 256) {
        float cnt = ws[WS_CNT + i / KDIM];
        lmean[i] = ws[WS_SUMS + i] / fmaxf(cnt, 1.0f);
    }
    if (tid < NCLS) lintra[tid] = 0.0f;
    __syncthreads();

    const int s = tid & 31;
    const int pp = tid >> 5;
    const int stride = GRID * 8;
    for (int p = blockIdx.x * 8 + pp; p < N; p += 2 * stride) {
        const int p1 = p + stride;
        {
            const int c = t[p];
            const float4 v = emb4[(size_t)p * 32 + s];
            const float4 m = *(const float4*)&lmean[c * KDIM + 4 * s];
            float dx = v.x - m.x, dy = v.y - m.y, dz = v.z - m.z, dw = v.w - m.w;
            float d2 = dx * dx + dy * dy + dz * dz + dw * dw;
            for (int off = 16; off >= 1; off >>= 1) d2 += __shfl_down(d2, off, 32);
            if (s == 0) {
                float d = sqrtf(d2);
                float px = pts[(size_t)p * 3 + 0];
                float py = pts[(size_t)p * 3 + 1];
                float pz = pts[(size_t)p * 3 + 2];
                float r = sqrtf(px * px + py * py + pz * pz);
                float g = 1.0f / (1.0f + expf(-r));
                float h = fmaxf(d - ALPHA, 0.0f);
                unsafeAtomicAdd(&lintra[c], g * h * h);
            }
        }
        if (p1 < N) {
            const int c = t[p1];
            const float4 v = emb4[(size_t)p1 * 32 + s];
            const float4 m = *(const float4*)&lmean[c * KDIM + 4 * s];
            float dx = v.x - m.x, dy = v.y - m.y, dz = v.z - m.z, dw = v.w - m.w;
            float d2 = dx * dx + dy * dy + dz * dz + dw * dw;
            for (int off = 16; off >= 1; off >>= 1) d2 += __shfl_down(d2, off, 32);
            if (s == 0) {
                float d = sqrtf(d2);
                float px = pts[(size_t)p1 * 3 + 0];
                float py = pts[(size_t)p1 * 3 + 1];
                float pz = pts[(size_t)p1 * 3 + 2];
                float r = sqrtf(px * px + py * py + pz * pz);
                float g = 1.0f / (1.0f + expf(-r));
                float h = fmaxf(d - ALPHA, 0.0f);
                unsafeAtomicAdd(&lintra[c], g * h * h);
            }
        }
    }
    __syncthreads();
    if (tid < NCLS) unsafeAtomicAdd(&ws[WS_INTRA + tid], lintra[tid]);
}

// ---- final (unchanged) ----
__global__ void __launch_bounds__(256) k_final(const float* __restrict__ ws,
                                               float* __restrict__ out) {
    __shared__ float lmean[NCLS * KDIM];
    __shared__ float red[256];
    const int tid = threadIdx.x;
    for (int i = tid; i < NCLS * KDIM; i += 256) {
        float cnt = ws[WS_CNT + i / KDIM];
        lmean[i] = ws[WS_SUMS + i] / fmaxf(cnt, 1.0f);
    }
    __syncthreads();

    float acc = 0.0f;
    for (int idx = tid; idx < 361; idx += 256) {
        int i = idx / 19 + 1;
        int j = idx % 19 + 1;
        if (i != j) {
            float sq = 0.0f;
            const float* mi = lmean + i * KDIM;
            const float* mj = lmean + j * KDIM;
            for (int k = 0; k < KDIM; k++) {
                float df = mi[k] - mj[k];
                sq += df * df;
            }
            float dist = sqrtf(sq);
            float h = fmaxf(BETA - dist, 0.0f);
            acc += h * h;
        }
    }
    red[tid] = acc;
    __syncthreads();
    for (int st = 128; st >= 1; st >>= 1) {
        if (tid < st) red[tid] += red[tid + st];
        __syncthreads();
    }
    if (tid == 0) {
        float intra = 0.0f;
        for (int c = 1; c < NCLS; c++) {
            intra += ws[WS_INTRA + c] / fmaxf(ws[WS_CNT + c], 1.0f);
        }
        out[0] = intra / (float)NCLS + red[0] / (float)(NCLS * (NCLS - 1));
    }
}

extern "C" void kernel_launch(void* const* d_in, const int* in_sizes, int n_in,
                              void* d_out, int out_size, void* d_ws, size_t ws_size,
                              hipStream_t stream) {
    const float* pts = (const float*)d_in[0];
    const int* t = (const int*)d_in[1];
    const int4* t4 = (const int4*)d_in[1];
    const float4* emb4 = (const float4*)d_in[2];
    float* out = (float*)d_out;
    float* ws = (float*)d_ws;
    const int N = in_sizes[1];
    const int N4 = N / 4;

    k_init<<<(WS_ZERO + 255) / 256, 256, 0, stream>>>(ws);

    if (ws_size >= (size_t)WS_NEEDED && (N % 4) == 0) {
        k_hist<<<(N4 + 255) / 256, 256, 0, stream>>>(t4, ws, N4);
        k_scan<<<1, 64, 0, stream>>>(ws);
        k_scatter<<<(N4 + 255) / 256, 256, 0, stream>>>(t4, ws, N4);
        k_sums<<<SUMS_GRID, 256, 0, stream>>>(emb4, ws, ws, N);
    } else {
        k_sums_fb<<<FB_GRID, FB_BLK, 0, stream>>>(emb4, t, ws, N);
    }
    k_intra<<<GRID, 256, 0, stream>>>(emb4, t, pts, ws, N);
    k_final<<<1, 256, 0, stream>>>(ws, out);
}